// Round 3
// baseline (5450.629 us; speedup 1.0000x reference)
//
#include <hip/hip_runtime.h>

typedef unsigned short u16;
typedef unsigned int u32;

// ---------- bf16 helpers (LDS compression of LN1 output only) ----------
__device__ __forceinline__ float bf2f(u16 b) { return __uint_as_float(((u32)b) << 16); }
__device__ __forceinline__ u16 f2bf(float f) {
  u32 u = __float_as_uint(f);
  u32 r = u + 0x7fffu + ((u >> 16) & 1u);   // round-nearest-even
  return (u16)(r >> 16);
}
__device__ __forceinline__ void up4(uint2 p, float& a, float& b, float& c, float& d) {
  a = bf2f((u16)(p.x & 0xffffu)); b = bf2f((u16)(p.x >> 16));
  c = bf2f((u16)(p.y & 0xffffu)); d = bf2f((u16)(p.y >> 16));
}
__device__ __forceinline__ float wsum(float v) {
  #pragma unroll
  for (int o = 32; o > 0; o >>= 1) v += __shfl_down(v, o);
  return __shfl(v, 0);
}
__device__ __forceinline__ float wmax(float v) {
  #pragma unroll
  for (int o = 32; o > 0; o >>= 1) v = fmaxf(v, __shfl_down(v, o));
  return __shfl(v, 0);
}

// ---------- K0: transpose f32 [R][Cc] -> [Cc][R] ----------
__global__ void k_trf(const float* __restrict__ in, float* __restrict__ out, int R, int Cc) {
  int e = blockIdx.x * 256 + threadIdx.x;
  if (e < R * Cc) {
    int r = e / Cc, c = e - r * Cc;
    out[(size_t)c * R + r] = in[e];
  }
}

// ---------- K1: LN1 + shift + window + qkv + attn + softmax + P@V + proj + residual ----------
// one block per window (2048), 256 threads; writes x1 (f32) into d_out
__global__ __launch_bounds__(256) void k_attn_proj(
    const float* __restrict__ x, const float* __restrict__ qkvT,
    const float* __restrict__ qkvb, const float* __restrict__ g1,
    const float* __restrict__ b1, const float* __restrict__ temp,
    const int* __restrict__ rpi, const float* __restrict__ rtab,
    const float* __restrict__ amask, const float* __restrict__ pw,
    const float* __restrict__ pb, float* __restrict__ io) {
  __shared__ __align__(16) char smem[54096];
  u16 (*zn_s)[256]    = (u16 (*)[256])smem;            //     0 .. 25088  LN out, bf16
  float (*q_s)[33]    = (float (*)[33])(smem + 25088); // 25088 .. 31556
  float (*k_s)[33]    = (float (*)[33])(smem + 31556); // 31556 .. 38024
  float (*v_s)[33]    = (float (*)[33])(smem + 38024); // 38024 .. 44492
  float (*attn_s)[49] = (float (*)[49])(smem + 44492); // 44492 .. 54096
  float* o_hT         = (float*)(smem + 25088);        // [32][52] overlay on dead q/k scratch

  const int tid = threadIdx.x;
  const int lane = tid & 63, wv = tid >> 6;
  const int col = tid & 31, grp = tid >> 5;
  const int win = blockIdx.x;
  const int b = win >> 6, wimg = win & 63;      // wimg = attn_mask row (hb*8+wb)
  const int hb = wimg >> 3, wb = wimg & 7;
  const float scale = expf(temp[0]);

  // --- LN1 over C=256 at shifted source coords (roll(-3): src = dst+3 mod 56) ---
  {
    const float4 gz = ((const float4*)g1)[lane];
    const float4 bz = ((const float4*)b1)[lane];
    for (int n = wv; n < 49; n += 4) {
      int i = n / 7, j = n - 7 * i;
      int rs = hb * 7 + i + 3; if (rs >= 56) rs -= 56;
      int cs = wb * 7 + j + 3; if (cs >= 56) cs -= 56;
      const float4 p = ((const float4*)(x + ((size_t)b * 3136 + rs * 56 + cs) * 256))[lane];
      float mean = wsum(p.x + p.y + p.z + p.w) * (1.f / 256.f);
      float d0 = p.x - mean, d1 = p.y - mean, d2 = p.z - mean, d3 = p.w - mean;
      float var = wsum(d0 * d0 + d1 * d1 + d2 * d2 + d3 * d3) * (1.f / 256.f);
      float rstd = rsqrtf(var + 1e-6f);
      u32 lo = (u32)f2bf(d0 * rstd * gz.x + bz.x) | ((u32)f2bf(d1 * rstd * gz.y + bz.y) << 16);
      u32 hi = (u32)f2bf(d2 * rstd * gz.z + bz.z) | ((u32)f2bf(d3 * rstd * gz.w + bz.w) << 16);
      ((uint2*)&zn_s[n][0])[lane] = make_uint2(lo, hi);
    }
  }
  __syncthreads();

  float acc49[49];          // proj accumulator: token n, channel cc=tid
  #pragma unroll
  for (int n = 0; n < 49; ++n) acc49[n] = 0.f;

  for (int h = 0; h < 8; ++h) {
    // --- q/k/v head slice: (49x256)@(256x32); weights streamed once per head ---
    {
      const float bq = qkvb[h * 32 + col];
      const float bk = qkvb[256 + h * 32 + col];
      const float bv = qkvb[512 + h * 32 + col];
      const float4* wqp = (const float4*)(qkvT + (size_t)(h * 32 + col) * 256);
      const float4* wkp = (const float4*)(qkvT + (size_t)(256 + h * 32 + col) * 256);
      const float4* wvp = (const float4*)(qkvT + (size_t)(512 + h * 32 + col) * 256);
      float aq[7], ak[7], av[7];
      #pragma unroll
      for (int t = 0; t < 7; ++t) { aq[t] = 0.f; ak[t] = 0.f; av[t] = 0.f; }
      for (int c4 = 0; c4 < 64; ++c4) {
        const float4 wq4 = wqp[c4], wk4 = wkp[c4], wv4 = wvp[c4];
        #pragma unroll
        for (int t = 0; t < 7; ++t) {
          const int n = grp + 8 * t;
          if (n < 49) {
            uint2 zp = ((const uint2*)&zn_s[n][0])[c4];
            float z0, z1, z2, z3; up4(zp, z0, z1, z2, z3);
            aq[t] += z0 * wq4.x + z1 * wq4.y + z2 * wq4.z + z3 * wq4.w;
            ak[t] += z0 * wk4.x + z1 * wk4.y + z2 * wk4.z + z3 * wk4.w;
            av[t] += z0 * wv4.x + z1 * wv4.y + z2 * wv4.z + z3 * wv4.w;
          }
        }
      }
      #pragma unroll
      for (int t = 0; t < 7; ++t) {
        const int n = grp + 8 * t;
        if (n < 49) {
          q_s[n][col] = (aq[t] + bq) * scale;   // fold exp(temperature) into q
          k_s[n][col] = ak[t] + bk;
          v_s[n][col] = av[t] + bv;
        }
      }
    }
    __syncthreads();

    // --- scores: diag=-inf BEFORE bias/mask (per reference), + bias + shift-mask ---
    for (int e = tid; e < 2401; e += 256) {
      int n = e / 49, m = e - 49 * n;
      float s;
      if (n == m) {
        s = -1e30f;
      } else {
        s = 0.f;
        #pragma unroll
        for (int d = 0; d < 32; ++d) s += q_s[n][d] * k_s[m][d];
      }
      s += rtab[(size_t)rpi[e] * 8 + h] + amask[(size_t)wimg * 2401 + e];
      attn_s[n][m] = s;
    }
    __syncthreads();

    // --- softmax per row ---
    for (int n = wv; n < 49; n += 4) {
      float s = (lane < 49) ? attn_s[n][lane] : -3.0e38f;
      float mx = wmax(s);
      float e = (lane < 49) ? expf(s - mx) : 0.f;
      float sum = wsum(e);
      if (lane < 49) attn_s[n][lane] = e / sum;
    }
    __syncthreads();

    // --- P@V -> o_hT[col][n] (q/k scratch is dead now) ---
    #pragma unroll
    for (int t = 0; t < 7; ++t) {
      const int n = grp + 8 * t;
      if (n < 49) {
        float a = 0.f;
        #pragma unroll
        for (int m = 0; m < 49; ++m) a += attn_s[n][m] * v_s[m][col];
        o_hT[col * 52 + n] = a;
      }
    }
    __syncthreads();

    // --- proj partial: acc49[n] += o_h[n][c2] * pw[h*32+c2][cc] ---
    {
      const int cc = tid;
      for (int c2 = 0; c2 < 32; ++c2) {
        const float w = pw[(size_t)(h * 32 + c2) * 256 + cc];
        const float4* row = (const float4*)(o_hT + c2 * 52);
        #pragma unroll
        for (int n4 = 0; n4 < 12; ++n4) {
          const float4 o4 = row[n4];
          acc49[n4 * 4 + 0] += o4.x * w; acc49[n4 * 4 + 1] += o4.y * w;
          acc49[n4 * 4 + 2] += o4.z * w; acc49[n4 * 4 + 3] += o4.w * w;
        }
        acc49[48] += o_hT[c2 * 52 + 48] * w;
      }
    }
    __syncthreads();   // protect o_hT/q/k/v before next head
  }

  // --- reverse shift + residual -> x1 (f32) ---
  {
    const int cc = tid;
    const float pbv = pb[cc];
    #pragma unroll
    for (int n = 0; n < 49; ++n) {
      int i = n / 7, j = n - 7 * i;
      int rs = hb * 7 + i + 3; if (rs >= 56) rs -= 56;  // win_reverse + roll(+3)
      int cs = wb * 7 + j + 3; if (cs >= 56) cs -= 56;
      size_t dst = ((size_t)b * 3136 + rs * 56 + cs) * 256 + cc;
      io[dst] = x[dst] + acc49[n] + pbv;
    }
  }
}

// ---------- K2: LN2 + fc1 + GELU + fc2 + residual (in-place on d_out rows, f32) ----------
__global__ __launch_bounds__(256) void k_mlp(
    float* __restrict__ io, const float* __restrict__ g2, const float* __restrict__ b2,
    const float* __restrict__ fc1T, const float* __restrict__ fb1,
    const float* __restrict__ w2p, const float* __restrict__ fb2) {
  __shared__ __align__(16) float ln_s[32][256];
  __shared__ __align__(16) float t1T[64][36];
  const int tid = threadIdx.x;
  const int lane = tid & 63, wv = tid >> 6;
  const size_t t0 = (size_t)blockIdx.x * 32;

  // --- LN2 (reads f32 x1) ---
  {
    const float4 gz = ((const float4*)g2)[lane];
    const float4 bz = ((const float4*)b2)[lane];
    for (int n = wv; n < 32; n += 4) {
      const float4 p = ((const float4*)(io + (t0 + n) * 256))[lane];
      float mean = wsum(p.x + p.y + p.z + p.w) * (1.f / 256.f);
      float d0 = p.x - mean, d1 = p.y - mean, d2 = p.z - mean, d3 = p.w - mean;
      float var = wsum(d0 * d0 + d1 * d1 + d2 * d2 + d3 * d3) * (1.f / 256.f);
      float rstd = rsqrtf(var + 1e-6f);
      ((float4*)&ln_s[n][0])[lane] =
          make_float4(d0 * rstd * gz.x + bz.x, d1 * rstd * gz.y + bz.y,
                      d2 * rstd * gz.z + bz.z, d3 * rstd * gz.w + bz.w);
    }
  }
  __syncthreads();

  float acc32[32];
  #pragma unroll
  for (int n = 0; n < 32; ++n) acc32[n] = 0.f;
  const int col = lane;

  for (int ch = 0; ch < 16; ++ch) {
    // --- fc1 chunk: t1 = gelu(ln @ W1[:, ch*64 .. +64) + b1) ---
    float acc8[8];
    #pragma unroll
    for (int r = 0; r < 8; ++r) acc8[r] = 0.f;
    const float4* wrow = (const float4*)(fc1T + (size_t)(ch * 64 + col) * 256);
    for (int c4 = 0; c4 < 64; ++c4) {
      const float4 w4 = wrow[c4];
      #pragma unroll
      for (int r = 0; r < 8; ++r) {
        const float4 l = ((const float4*)&ln_s[wv + (r << 2)][0])[c4];
        acc8[r] += l.x * w4.x + l.y * w4.y + l.z * w4.z + l.w * w4.w;
      }
    }
    {
      const float bb = fb1[ch * 64 + col];
      #pragma unroll
      for (int r = 0; r < 8; ++r) {
        float a = acc8[r] + bb;
        t1T[col][wv + (r << 2)] = 0.5f * a * (1.f + erff(a * 0.70710678118654752f));
      }
    }
    __syncthreads();
    // --- fc2 accumulate ---
    for (int m = 0; m < 64; ++m) {
      const float w = w2p[(size_t)(ch * 64 + m) * 256 + tid];
      const float4* tr = (const float4*)&t1T[m][0];
      #pragma unroll
      for (int n4 = 0; n4 < 8; ++n4) {
        const float4 t = tr[n4];
        acc32[n4 * 4 + 0] += t.x * w; acc32[n4 * 4 + 1] += t.y * w;
        acc32[n4 * 4 + 2] += t.z * w; acc32[n4 * 4 + 3] += t.w * w;
      }
    }
    __syncthreads();
  }

  const float b2v = fb2[tid];
  #pragma unroll
  for (int n = 0; n < 32; ++n) {
    size_t idx = (t0 + n) * 256 + tid;
    io[idx] = io[idx] + acc32[n] + b2v;   // out = x1 + mlp
  }
}

extern "C" void kernel_launch(void* const* d_in, const int* in_sizes, int n_in,
                              void* d_out, int out_size, void* d_ws, size_t ws_size,
                              hipStream_t stream) {
  const float* x     = (const float*)d_in[0];
  const float* amask = (const float*)d_in[1];
  const float* g1    = (const float*)d_in[2];
  const float* b1    = (const float*)d_in[3];
  const float* qkvw  = (const float*)d_in[4];
  const float* qkvb  = (const float*)d_in[5];
  const float* temp  = (const float*)d_in[6];
  const float* rtab  = (const float*)d_in[7];
  const float* pw    = (const float*)d_in[8];
  const float* pb    = (const float*)d_in[9];
  const float* g2    = (const float*)d_in[10];
  const float* b2    = (const float*)d_in[11];
  const float* w1    = (const float*)d_in[12];
  const float* fb1   = (const float*)d_in[13];
  const float* w2    = (const float*)d_in[14];
  const float* fb2   = (const float*)d_in[15];
  const int* rpi     = (const int*)d_in[16];
  // d_in[17], d_in[18] = H, W (fixed 56)

  char* ws = (char*)d_ws;
  float* qkvT = (float*)ws;                 // 786,432 B  (768x256 f32, k-contiguous)
  float* fc1T = (float*)(ws + 786432);      // 1,048,576 B (1024x256 f32, k-contiguous)
  float* io = (float*)d_out;                // x1 then final output (f32)

  k_trf<<<768, 256, 0, stream>>>(qkvw, qkvT, 256, 768);
  k_trf<<<1024, 256, 0, stream>>>(w1, fc1T, 256, 1024);
  k_attn_proj<<<2048, 256, 0, stream>>>(x, qkvT, qkvb, g1, b1, temp, rpi, rtab,
                                        amask, pw, pb, io);
  k_mlp<<<3136, 256, 0, stream>>>(io, g2, b2, fc1T, fb1, w2, fb2);
}